// Round 22
// baseline (141.538 us; speedup 1.0000x reference)
//
#include <hip/hip_runtime.h>
#include <cstdint>
#include <cstddef>

#define NHEAD 8
#define HDIM 32
#define DMODEL 256
#define NLEVEL 4
#define NPOINT 4

using short8 = __attribute__((ext_vector_type(8))) short;
using f32x4  = __attribute__((ext_vector_type(4))) float;

// ---- bf16 helpers (RNE) ----------------------------------------------------
__device__ __forceinline__ unsigned short f2bf(float x) {
    unsigned int b = __float_as_uint(x);
    unsigned int r = b + 0x7FFFu + ((b >> 16) & 1u);
    return (unsigned short)(r >> 16);
}
__device__ __forceinline__ float bf2f(unsigned short u) {
    return __uint_as_float(((unsigned int)u) << 16);
}
__device__ __forceinline__ unsigned short lo1(float v) {
    const unsigned short h = f2bf(v);
    return f2bf(v - bf2f(h));
}
__device__ __forceinline__ unsigned int pk2(unsigned short a, unsigned short b) {
    return (unsigned int)a | ((unsigned int)b << 16);
}
// async global->LDS, 16B per lane (dest = wave-uniform base + lane*16)
__device__ __forceinline__ void gld16(const unsigned short* g, unsigned short* l) {
    __builtin_amdgcn_global_load_lds(
        (const __attribute__((address_space(1))) void*)g,
        (__attribute__((address_space(3))) void*)l, 16, 0, 0);
}

// ---------------------------------------------------------------------------
// convall: ONE launch for all conversions.
//   blocks [0, nbAct): value -> Av, query -> Aq  ([hi|lo] per row)
//   blocks [nbAct, nbAct+192): four weight matrices -> Bv, Bo, Blg
// ---------------------------------------------------------------------------
__global__ __launch_bounds__(256) void convall(
    const float* __restrict__ value, const float* __restrict__ query,
    unsigned short* __restrict__ Av, unsigned short* __restrict__ Aq,
    int M2, int Mtot, int nbAct,
    const float* __restrict__ w0, const float* __restrict__ w1,
    const float* __restrict__ w2, const float* __restrict__ w3,
    unsigned short* __restrict__ b0, unsigned short* __restrict__ b1,
    unsigned short* __restrict__ blg)
{
    if ((int)blockIdx.x < nbAct) {
        const int idx = blockIdx.x * 256 + threadIdx.x;
        if (idx >= Mtot * 64) return;
        const int r = idx >> 6, c = (idx & 63) << 2;
        const float* src;
        unsigned short* dst;
        if (r < M2) { src = value + (size_t)r * 256; dst = Av + (size_t)r * 512; }
        else { src = query + (size_t)(r - M2) * 256; dst = Aq + (size_t)(r - M2) * 512; }
        const float4 v = *(const float4*)(src + c);
        ushort4 hi, lo;
        hi.x = f2bf(v.x); lo.x = lo1(v.x);
        hi.y = f2bf(v.y); lo.y = lo1(v.y);
        hi.z = f2bf(v.z); lo.z = lo1(v.z);
        hi.w = f2bf(v.w); lo.w = lo1(v.w);
        *(ushort4*)(dst + c)       = hi;
        *(ushort4*)(dst + 256 + c) = lo;
    } else {
        const int bx = (int)blockIdx.x - nbAct;           // 0..191
        int y, base;
        if (bx < 64)       { y = 0; base = bx; }
        else if (bx < 128) { y = 1; base = bx - 64; }
        else if (bx < 160) { y = 2; base = bx - 128; }
        else               { y = 3; base = bx - 160; }
        const float* src = (y == 0) ? w0 : (y == 1) ? w1 : (y == 2) ? w2 : w3;
        unsigned short* dst = (y == 0) ? b0 : (y == 1) ? b1 : (y == 2) ? blg : (blg + 128 * 512);
        const int rows = (y < 2) ? 256 : 128;
        const int idx = base * 256 + threadIdx.x;
        if (idx >= rows * 64) return;
        const int r = idx >> 6, c = (idx & 63) << 2;
        const float4 v = *(const float4*)(src + (size_t)r * 256 + c);
        ushort4 hi, lo;
        hi.x = f2bf(v.x); lo.x = lo1(v.x);
        hi.y = f2bf(v.y); lo.y = lo1(v.y);
        hi.z = f2bf(v.z); lo.z = lo1(v.z);
        hi.w = f2bf(v.w); lo.w = lo1(v.w);
        *(ushort4*)(dst + (size_t)r * 512 + c)       = hi;
        *(ushort4*)(dst + (size_t)r * 512 + 256 + c) = lo;
    }
}

// ---------------------------------------------------------------------------
// Split-bf16 MFMA GEMM, BM=32 x BN=256, BK=32, 24 steps, single-buffered.
// K'=768: A segs [hi,hi,lo] x B segs [hi,lo,hi] (C = AhBh+AhBl+AlBh).
// STAGING VIA global_load_lds (16B/lane): removes 20 staging VGPRs + addr
// VALU (R18-21: latency-bound at VGPR-capped ~18 waves/CU). LDS dest is
// linear (wave base + lane*16, rule #21), so the R20 bank swizzle moves to
// the GLOBAL source rows (m173 pattern): wave w owns k-slot w; lane l
// fetches global row (l&48)|((l&15)^(w<<2)); read side identical to R20
// (slot kg, row lrx) -- permutations verified to match.
// ---------------------------------------------------------------------------
template<int ID>
__global__ __launch_bounds__(256) void gemm_mfma(
    const unsigned short* __restrict__ A0, const unsigned short* __restrict__ B0,
    const float* __restrict__ bsA0, const float* __restrict__ bsB0, int bsplit0,
    const unsigned char* __restrict__ mask0, void* __restrict__ C0, int obf0, int M0, int nb0,
    const unsigned short* __restrict__ A1, const unsigned short* __restrict__ B1,
    const float* __restrict__ bsA1, const float* __restrict__ bsB1, int bsplit1,
    const unsigned char* __restrict__ mask1, void* __restrict__ C1, int obf1, int M1)
{
    __shared__ __align__(16) unsigned short As[4 * 32 * 8];    // 2KB  [slot][32 rows][8]
    __shared__ __align__(16) unsigned short Bs[4 * 256 * 8];   // 16KB [slot][256 rows][8]

    const bool second = ((int)blockIdx.x >= nb0);
    const unsigned short* Abf = second ? A1 : A0;
    const unsigned short* Bbf = second ? B1 : B0;
    const float* biasA = second ? bsA1 : bsA0;
    const float* biasB = second ? bsB1 : bsB0;
    const int bsplit   = second ? bsplit1 : bsplit0;
    const unsigned char* maskp = second ? mask1 : mask0;
    void* Cv    = second ? C1 : C0;
    const int obf = second ? obf1 : obf0;
    const int M = second ? M1 : M0;
    const int row0 = (second ? ((int)blockIdx.x - nb0) : (int)blockIdx.x) * 32;

    const int tid  = threadIdx.x;
    const int lane = tid & 63;
    const int wave = tid >> 6;
    const int lr = lane & 15;
    const int kg = lane >> 4;
    const int lrx = lr ^ (kg << 2);

    // ---- gload_lds source rows (pre-swizzled) / linear LDS dests ----
    // A: waves 0,1 issue; slot s = wave*2 + (lane>>5); row p = lane&31
    const int aS = wave * 2 + (lane >> 5);
    const int aP = lane & 31;
    const int aG = min(row0 + (aP & 16) + ((aP & 15) ^ (aS << 2)), M - 1);
    const unsigned short* pA = Abf + (size_t)aG * 512 + aS * 8;
    unsigned short* dA = &As[(size_t)tid * 8];               // == aS*256 + aP*8

    // B: slot = wave; issue k covers rows lane+64k
    const int bG0 = (lane & 48) + ((lane & 15) ^ (wave << 2));
    const unsigned short* pB = Bbf + (size_t)bG0 * 512 + wave * 8;
    unsigned short* dB = &Bs[(size_t)wave * 2048 + lane * 8];

    f32x4 acc[2][4];
#pragma unroll
    for (int m = 0; m < 2; ++m)
#pragma unroll
        for (int n = 0; n < 4; ++n) acc[m][n] = {0.f, 0.f, 0.f, 0.f};

    for (int st = 0; st < 24; ++st) {
        const int seg  = st >> 3;
        const int kl   = (st & 7) << 5;
        const int aoff = (seg < 2)  ? kl : 256 + kl;   // A: [hi,hi,lo]
        const int boff = (seg == 1) ? 256 + kl : kl;   // B: [hi,lo,hi]

        if (tid < 128) gld16(pA + aoff, dA);
        gld16(pB + boff,                 dB);
        gld16(pB + boff + (size_t)64  * 512, dB + 512);
        gld16(pB + boff + (size_t)128 * 512, dB + 1024);
        gld16(pB + boff + (size_t)192 * 512, dB + 1536);
        __syncthreads();   // drains vmcnt -> LDS writes complete; waves synced

        const short8 a0 = *(const short8*)&As[kg * 256 + (lrx     ) * 8];
        const short8 a1 = *(const short8*)&As[kg * 256 + (lrx + 16) * 8];
#pragma unroll
        for (int n = 0; n < 4; ++n) {
            const short8 bb = *(const short8*)&Bs[kg * 2048 + (wave * 64 + n * 16 + lrx) * 8];
            acc[0][n] = __builtin_amdgcn_mfma_f32_16x16x32_bf16(a0, bb, acc[0][n], 0, 0, 0);
            acc[1][n] = __builtin_amdgcn_mfma_f32_16x16x32_bf16(a1, bb, acc[1][n], 0, 0, 0);
        }
        __syncthreads();   // reads done before next step's DMA writes
    }

    // epilogue: C/D layout col=lane&15, row=(lane>>4)*4+j  [m89-verified]
#pragma unroll
    for (int m = 0; m < 2; ++m) {
#pragma unroll
        for (int n = 0; n < 4; ++n) {
            const int colg = wave * 64 + n * 16 + lr;
            const float bias = (colg < bsplit) ? biasA[colg] : biasB[colg - bsplit];
#pragma unroll
            for (int j = 0; j < 4; ++j) {
                const int rowg = row0 + m * 16 + kg * 4 + j;
                if (rowg < M) {
                    float o = acc[m][n][j] + bias;
                    if (maskp && maskp[rowg]) o = 0.f;
                    if (obf) ((unsigned short*)Cv)[(size_t)rowg * 256 + colg] = f2bf(o);
                    else     ((float*)Cv)[(size_t)rowg * 256 + colg] = o;
                }
            }
        }
    }
}

// ---------------------------------------------------------------------------
// Box-attention sampling (R21-proven: ~37us). bf16-v + point-split + TLP
// (__launch_bounds__(256,5), unroll 4). Output: split-bf16 [hi|lo].
// ---------------------------------------------------------------------------
#define ROWS 4
#define PP 17

__global__ __launch_bounds__(256, 5) void box_sample(
    const unsigned short* __restrict__ v, // (B*L2, 256) bf16 projected value
    const float* __restrict__ alogp,  // attn logits base (stride 256)
    const float* __restrict__ blgp,   // box logits base (stride 256)
    const float* __restrict__ rwin,
    const float* __restrict__ vratio,
    unsigned short* __restrict__ outs, // (B*L1, 512) split-bf16 out
    int M1, int L1, int L2)
{
    __shared__ int   s_idx[ROWS][NHEAD][PP][4];
    __shared__ float s_w  [ROWS][NHEAD][PP][4];
    __shared__ float s_red[ROWS][NHEAD][4][8];   // point-half reduction (4KB)

    const int row0 = blockIdx.x * ROWS;
    const int tid  = threadIdx.x;

    // ================= phase 1 (first 128 threads) =================
    if (tid < 128) {
        const int l  = tid & 3;
        const int hh = (tid >> 2) & 7;
        const int r  = tid >> 5;
        const int rowq = row0 + r;
        if (rowq < M1) {
            const int b = (rowq >= L1) ? 1 : 0;
            float la[16];
            const float* al = alogp + (size_t)rowq * 256 + hh * 16;
            {
                const float4 q0 = *(const float4*)(al + 0);
                const float4 q1 = *(const float4*)(al + 4);
                const float4 q2 = *(const float4*)(al + 8);
                const float4 q3 = *(const float4*)(al + 12);
                la[0]=q0.x; la[1]=q0.y; la[2]=q0.z; la[3]=q0.w;
                la[4]=q1.x; la[5]=q1.y; la[6]=q1.z; la[7]=q1.w;
                la[8]=q2.x; la[9]=q2.y; la[10]=q2.z; la[11]=q2.w;
                la[12]=q3.x; la[13]=q3.y; la[14]=q3.z; la[15]=q3.w;
            }
            float m = la[0];
#pragma unroll
            for (int i = 1; i < 16; i++) m = fmaxf(m, la[i]);
            float s = 0.f;
#pragma unroll
            for (int i = 0; i < 16; i++) { la[i] = __expf(la[i] - m); s += la[i]; }
            const float inv = 1.f / s;

            const int H  = (l == 0) ? 76 : (l == 1) ? 38 : (l == 2) ? 19 : 10;
            const int W  = H;
            const int s0 = (l == 0) ? 0  : (l == 1) ? 5776 : (l == 2) ? 7220 : 7581;

            const float4 ob = *(const float4*)(blgp + (size_t)rowq * 256 + hh * 16 + l * 4);
            const float4 rw = *(const float4*)(rwin + (size_t)rowq * 4);
            const float vrx = vratio[(b * NLEVEL + l) * 2 + 0];
            const float vry = vratio[(b * NLEVEL + l) * 2 + 1];

            const float cx = rw.x + ob.x * 0.125f * rw.z;
            const float cy = rw.y + ob.y * 0.125f * rw.w;
            const float sw = fmaxf(rw.z + ob.z * 0.125f * rw.z, 0.f);
            const float sh = fmaxf(rw.w + ob.w * 0.125f * rw.w, 0.f);

            const int vbase = (b * L2 + s0) * DMODEL + hh * HDIM;  // ushort units

#pragma unroll
            for (int p = 0; p < 4; ++p) {
                const float kx = (p & 1)  ? 0.25f : -0.25f;
                const float ky = (p >> 1) ? 0.25f : -0.25f;
                const float gx = (cx + kx * sw) * vrx;
                const float gy = (cy + ky * sh) * vry;
                const float x = gx * (float)W - 0.5f;
                const float y = gy * (float)H - 0.5f;
                const float x0f = floorf(x);
                const float y0f = floorf(y);
                const float lx = x - x0f, ly = y - y0f;
                const int x0 = (int)x0f, y0 = (int)y0f;
                const float aw = la[l * 4 + p] * inv;
                const float wb[4] = { (1.f - ly) * (1.f - lx) * aw,
                                      (1.f - ly) * lx * aw,
                                      ly * (1.f - lx) * aw,
                                      ly * lx * aw };
                const int lp = l * 4 + p;
#pragma unroll
                for (int j = 0; j < 4; ++j) {
                    const int yy = y0 + (j >> 1);
                    const int xx = x0 + (j & 1);
                    const bool ok = (yy >= 0) & (yy < H) & (xx >= 0) & (xx < W);
                    const int yc = min(max(yy, 0), H - 1);
                    const int xc = min(max(xx, 0), W - 1);
                    s_idx[r][hh][lp][j] = vbase + (yc * W + xc) * DMODEL;
                    s_w  [r][hh][lp][j] = ok ? wb[j] : 0.f;
                }
            }
        }
    }
    __syncthreads();

    // ================= phase 2: point-split ushort8 gathers =================
    {
        const int oct = tid & 3;            // channel octet 0..3
        const int hh  = (tid >> 2) & 7;     // head
        const int ph  = (tid >> 5) & 1;     // point half
        const int r   = tid >> 6;           // row 0..3
        const int rowq = row0 + r;
        const int c8 = oct << 3;
        float acc[8];
#pragma unroll
        for (int k = 0; k < 8; ++k) acc[k] = 0.f;

        if (rowq < M1) {
            const int p0 = ph << 3;
#pragma unroll 4
            for (int pi = 0; pi < 8; ++pi) {
                const int p = p0 + pi;
                const int4   iv = *(const int4  *)&s_idx[r][hh][p][0];
                const float4 wv = *(const float4*)&s_w  [r][hh][p][0];
                const uint4 g0 = *(const uint4*)(v + iv.x + c8);
                const uint4 g1 = *(const uint4*)(v + iv.y + c8);
                const uint4 g2 = *(const uint4*)(v + iv.z + c8);
                const uint4 g3 = *(const uint4*)(v + iv.w + c8);
                const unsigned int u0[4] = {g0.x, g0.y, g0.z, g0.w};
                const unsigned int u1[4] = {g1.x, g1.y, g1.z, g1.w};
                const unsigned int u2[4] = {g2.x, g2.y, g2.z, g2.w};
                const unsigned int u3[4] = {g3.x, g3.y, g3.z, g3.w};
#pragma unroll
                for (int j = 0; j < 4; ++j) {
                    const float a0 = __uint_as_float(u0[j] << 16);
                    const float b0 = __uint_as_float(u0[j] & 0xffff0000u);
                    const float a1 = __uint_as_float(u1[j] << 16);
                    const float b1 = __uint_as_float(u1[j] & 0xffff0000u);
                    const float a2 = __uint_as_float(u2[j] << 16);
                    const float b2 = __uint_as_float(u2[j] & 0xffff0000u);
                    const float a3 = __uint_as_float(u3[j] << 16);
                    const float b3 = __uint_as_float(u3[j] & 0xffff0000u);
                    acc[j * 2]     += wv.x * a0 + wv.y * a1 + wv.z * a2 + wv.w * a3;
                    acc[j * 2 + 1] += wv.x * b0 + wv.y * b1 + wv.z * b2 + wv.w * b3;
                }
            }
        }

        // reduce the two point-halves via LDS
        if (ph == 1) {
#pragma unroll
            for (int k = 0; k < 8; ++k) s_red[r][hh][oct][k] = acc[k];
        }
        __syncthreads();
        if (ph == 0 && rowq < M1) {
#pragma unroll
            for (int k = 0; k < 8; ++k) acc[k] += s_red[r][hh][oct][k];
            uint4 hi, lo;
            hi.x = pk2(f2bf(acc[0]), f2bf(acc[1]));
            hi.y = pk2(f2bf(acc[2]), f2bf(acc[3]));
            hi.z = pk2(f2bf(acc[4]), f2bf(acc[5]));
            hi.w = pk2(f2bf(acc[6]), f2bf(acc[7]));
            lo.x = pk2(lo1(acc[0]), lo1(acc[1]));
            lo.y = pk2(lo1(acc[2]), lo1(acc[3]));
            lo.z = pk2(lo1(acc[4]), lo1(acc[5]));
            lo.w = pk2(lo1(acc[6]), lo1(acc[7]));
            *(uint4*)(outs + (size_t)rowq * 512 + hh * HDIM + c8)       = hi;
            *(uint4*)(outs + (size_t)rowq * 512 + 256 + hh * HDIM + c8) = lo;
        }
    }
}

// ---------------------------------------------------------------------------
extern "C" void kernel_launch(void* const* d_in, const int* in_sizes, int n_in,
                              void* d_out, int out_size, void* d_ws, size_t ws_size,
                              hipStream_t stream) {
    const float* query   = (const float*)d_in[0];
    const float* value   = (const float*)d_in[1];
    const unsigned char* v_mask = (const unsigned char*)d_in[3];
    const float* v_valid = (const float*)d_in[5];
    const float* ref_win = (const float*)d_in[6];
    const float* vproj_w = (const float*)d_in[7];
    const float* vproj_b = (const float*)d_in[8];
    const float* oproj_w = (const float*)d_in[9];
    const float* oproj_b = (const float*)d_in[10];
    const float* box_w   = (const float*)d_in[11];
    const float* box_b   = (const float*)d_in[12];
    const float* attn_w  = (const float*)d_in[13];
    const float* attn_b  = (const float*)d_in[14];

    const int B  = 2;
    const int M1 = in_sizes[0] / DMODEL;   // B*L1
    const int M2 = in_sizes[1] / DMODEL;   // B*L2
    const int L1 = M1 / B;
    const int L2 = M2 / B;
    const dim3 blk(256);

    // ---- workspace plan: Av | Aq(->OutS) | vprj(bf16) | weights; lgt in d_out
    const size_t szAv = (size_t)M2 * 512 * 2;
    const size_t szAq = (size_t)M1 * 512 * 2;
    char* wsb = (char*)d_ws;
    unsigned short* Av   = (unsigned short*)(wsb);
    unsigned short* Aq   = (unsigned short*)(wsb + szAv);
    unsigned short* OutS = Aq;                       // alias: Aq dead after GEMM
    unsigned short* vprj = (unsigned short*)(wsb + szAv + szAq);   // bf16 M2*256
    unsigned short* Bv   = (unsigned short*)(wsb + szAv + szAq + (size_t)M2 * 256 * 2);
    unsigned short* Bo   = Bv + 256 * 512;
    unsigned short* Blg  = Bo + 256 * 512;
    float*          lgt  = (float*)d_out;            // scratch until final GEMM

    const int mb1 = (M1 + 31) / 32;
    const int mb2 = (M2 + 31) / 32;
    const int nbAct = ((M2 + M1) * 64 + 255) / 256;

    // 1) ALL conversions in one launch (activations + 4 weight matrices)
    convall<<<dim3(nbAct + 192), blk, 0, stream>>>(
        value, query, Av, Aq, M2, M2 + M1, nbAct,
        vproj_w, oproj_w, attn_w, box_w, Bv, Bo, Blg);

    // 2) MERGED: value projection (+mask, bf16 out) AND combined logits (f32)
    gemm_mfma<0><<<dim3(mb2 + mb1), blk, 0, stream>>>(
        Av, Bv, vproj_b, vproj_b, 256, v_mask, (void*)vprj, 1, M2, mb2,
        Aq, Blg, attn_b, box_b, 128, nullptr, (void*)lgt, 0, M1);

    // 3) sampling (bf16 v gathers, point-split, TLP) -> split-bf16
    box_sample<<<dim3((M1 + ROWS - 1) / ROWS), blk, 0, stream>>>(
        vprj, lgt, lgt + 128, ref_win, v_valid, OutS, M1, L1, L2);

    // 4) output projection (reads OutS, overwrites d_out)
    gemm_mfma<1><<<dim3(mb1), blk, 0, stream>>>(
        OutS, Bo, oproj_b, oproj_b, 256, nullptr, d_out, 0, M1, mb1,
        OutS, Bo, oproj_b, oproj_b, 256, nullptr, d_out, 0, M1);
}

// Round 23
// 106.366 us; speedup vs baseline: 1.3307x; 1.3307x over previous
//
#include <hip/hip_runtime.h>
#include <cstdint>
#include <cstddef>

#define NHEAD 8
#define HDIM 32
#define DMODEL 256
#define NLEVEL 4
#define NPOINT 4

using short8 = __attribute__((ext_vector_type(8))) short;
using f32x4  = __attribute__((ext_vector_type(4))) float;

// ---- bf16 helpers (RNE) ----------------------------------------------------
__device__ __forceinline__ unsigned short f2bf(float x) {
    unsigned int b = __float_as_uint(x);
    unsigned int r = b + 0x7FFFu + ((b >> 16) & 1u);
    return (unsigned short)(r >> 16);
}
__device__ __forceinline__ float bf2f(unsigned short u) {
    return __uint_as_float(((unsigned int)u) << 16);
}
__device__ __forceinline__ unsigned short lo1(float v) {
    const unsigned short h = f2bf(v);
    return f2bf(v - bf2f(h));
}
__device__ __forceinline__ unsigned int pk2(unsigned short a, unsigned short b) {
    return (unsigned int)a | ((unsigned int)b << 16);
}

// ---------------------------------------------------------------------------
// convall: ONE launch for all conversions.
//   blocks [0, nbAct): value -> Av, query -> Aq  ([hi|lo] per row)
//   blocks [nbAct, nbAct+192): four weight matrices -> Bv, Bo, Blg
// ---------------------------------------------------------------------------
__global__ __launch_bounds__(256) void convall(
    const float* __restrict__ value, const float* __restrict__ query,
    unsigned short* __restrict__ Av, unsigned short* __restrict__ Aq,
    int M2, int Mtot, int nbAct,
    const float* __restrict__ w0, const float* __restrict__ w1,
    const float* __restrict__ w2, const float* __restrict__ w3,
    unsigned short* __restrict__ b0, unsigned short* __restrict__ b1,
    unsigned short* __restrict__ blg)
{
    if ((int)blockIdx.x < nbAct) {
        const int idx = blockIdx.x * 256 + threadIdx.x;
        if (idx >= Mtot * 64) return;
        const int r = idx >> 6, c = (idx & 63) << 2;
        const float* src;
        unsigned short* dst;
        if (r < M2) { src = value + (size_t)r * 256; dst = Av + (size_t)r * 512; }
        else { src = query + (size_t)(r - M2) * 256; dst = Aq + (size_t)(r - M2) * 512; }
        const float4 v = *(const float4*)(src + c);
        ushort4 hi, lo;
        hi.x = f2bf(v.x); lo.x = lo1(v.x);
        hi.y = f2bf(v.y); lo.y = lo1(v.y);
        hi.z = f2bf(v.z); lo.z = lo1(v.z);
        hi.w = f2bf(v.w); lo.w = lo1(v.w);
        *(ushort4*)(dst + c)       = hi;
        *(ushort4*)(dst + 256 + c) = lo;
    } else {
        const int bx = (int)blockIdx.x - nbAct;           // 0..191
        int y, base;
        if (bx < 64)       { y = 0; base = bx; }
        else if (bx < 128) { y = 1; base = bx - 64; }
        else if (bx < 160) { y = 2; base = bx - 128; }
        else               { y = 3; base = bx - 160; }
        const float* src = (y == 0) ? w0 : (y == 1) ? w1 : (y == 2) ? w2 : w3;
        unsigned short* dst = (y == 0) ? b0 : (y == 1) ? b1 : (y == 2) ? blg : (blg + 128 * 512);
        const int rows = (y < 2) ? 256 : 128;
        const int idx = base * 256 + threadIdx.x;
        if (idx >= rows * 64) return;
        const int r = idx >> 6, c = (idx & 63) << 2;
        const float4 v = *(const float4*)(src + (size_t)r * 256 + c);
        ushort4 hi, lo;
        hi.x = f2bf(v.x); lo.x = lo1(v.x);
        hi.y = f2bf(v.y); lo.y = lo1(v.y);
        hi.z = f2bf(v.z); lo.z = lo1(v.z);
        hi.w = f2bf(v.w); lo.w = lo1(v.w);
        *(ushort4*)(dst + (size_t)r * 512 + c)       = hi;
        *(ushort4*)(dst + (size_t)r * 512 + 256 + c) = lo;
    }
}

// ---------------------------------------------------------------------------
// Split-bf16 MFMA GEMM, BM=32 x BN=256, BK=32, 24 steps, single-buffered,
// slot-major XOR-swizzled LDS (18KB), REGISTER PREFETCH (R21-proven; R22's
// global_load_lds serialized each step -- the prefetch overlap is essential).
// __launch_bounds__(256,5): cap VGPR ~102 (R18 measured 112 -> 4 waves/EU;
// this buys a 5th wave/EU, +25% TLP; staging 20 + acc 32 fits w/o spill).
// K'=768: A segs [hi,hi,lo] x B segs [hi,lo,hi] (C = AhBh+AhBl+AlBh).
// Two sub-GEMMs merged per launch. obf: bf16 C-write for vprj.
// ---------------------------------------------------------------------------
template<int ID>
__global__ __launch_bounds__(256, 5) void gemm_mfma(
    const unsigned short* __restrict__ A0, const unsigned short* __restrict__ B0,
    const float* __restrict__ bsA0, const float* __restrict__ bsB0, int bsplit0,
    const unsigned char* __restrict__ mask0, void* __restrict__ C0, int obf0, int M0, int nb0,
    const unsigned short* __restrict__ A1, const unsigned short* __restrict__ B1,
    const float* __restrict__ bsA1, const float* __restrict__ bsB1, int bsplit1,
    const unsigned char* __restrict__ mask1, void* __restrict__ C1, int obf1, int M1)
{
    __shared__ __align__(16) unsigned short As[4 * 32 * 8];    // 2KB  [slot][32 rows][8]
    __shared__ __align__(16) unsigned short Bs[4 * 256 * 8];   // 16KB [slot][256 rows][8]

    const bool second = ((int)blockIdx.x >= nb0);
    const unsigned short* Abf = second ? A1 : A0;
    const unsigned short* Bbf = second ? B1 : B0;
    const float* biasA = second ? bsA1 : bsA0;
    const float* biasB = second ? bsB1 : bsB0;
    const int bsplit   = second ? bsplit1 : bsplit0;
    const unsigned char* maskp = second ? mask1 : mask0;
    void* Cv    = second ? C1 : C0;
    const int obf = second ? obf1 : obf0;
    const int M = second ? M1 : M0;
    const int row0 = (second ? ((int)blockIdx.x - nb0) : (int)blockIdx.x) * 32;

    const int tid  = threadIdx.x;
    const int lane = tid & 63;
    const int wave = tid >> 6;
    const int lr = lane & 15;
    const int kg = lane >> 4;
    const int lrx = lr ^ (kg << 2);

    const int ar = tid >> 2;
    const int as = tid & 3;
    const int br = tid >> 2;
    const int bs = tid & 3;
    const int arx = ar ^ (as << 2);
    const int brx = br ^ (bs << 2);

    const unsigned short* pA  = Abf + (size_t)min(row0 + ar, M - 1) * 512 + as * 8;
    const unsigned short* pB0 = Bbf + (size_t)(br      ) * 512 + bs * 8;
    const unsigned short* pB1 = Bbf + (size_t)(br + 64 ) * 512 + bs * 8;
    const unsigned short* pB2 = Bbf + (size_t)(br + 128) * 512 + bs * 8;
    const unsigned short* pB3 = Bbf + (size_t)(br + 192) * 512 + bs * 8;

    f32x4 acc[2][4];
#pragma unroll
    for (int m = 0; m < 2; ++m)
#pragma unroll
        for (int n = 0; n < 4; ++n) acc[m][n] = {0.f, 0.f, 0.f, 0.f};

    // prefetch step 0 (seg0: aoff=boff=0)
    uint4 va, vb0, vb1, vb2, vb3;
    if (tid < 128) va = *(const uint4*)pA;
    vb0 = *(const uint4*)pB0; vb1 = *(const uint4*)pB1;
    vb2 = *(const uint4*)pB2; vb3 = *(const uint4*)pB3;

    for (int st = 0; st < 24; ++st) {
        if (tid < 128) *(uint4*)&As[as * 256 + arx * 8] = va;
        *(uint4*)&Bs[bs * 2048 + (brx      ) * 8] = vb0;
        *(uint4*)&Bs[bs * 2048 + (brx + 64 ) * 8] = vb1;
        *(uint4*)&Bs[bs * 2048 + (brx + 128) * 8] = vb2;
        *(uint4*)&Bs[bs * 2048 + (brx + 192) * 8] = vb3;
        __syncthreads();   // writes visible before reads

        if (st < 23) {     // issue next step's loads; latency hides under MFMA
            const int sn   = st + 1;
            const int seg  = sn >> 3;
            const int kl   = (sn & 7) << 5;
            const int aoff = (seg < 2)  ? kl : 256 + kl;   // A: [hi,hi,lo]
            const int boff = (seg == 1) ? 256 + kl : kl;   // B: [hi,lo,hi]
            if (tid < 128) va = *(const uint4*)(pA + aoff);
            vb0 = *(const uint4*)(pB0 + boff); vb1 = *(const uint4*)(pB1 + boff);
            vb2 = *(const uint4*)(pB2 + boff); vb3 = *(const uint4*)(pB3 + boff);
        }

        const short8 a0 = *(const short8*)&As[kg * 256 + (lrx     ) * 8];
        const short8 a1 = *(const short8*)&As[kg * 256 + (lrx + 16) * 8];
#pragma unroll
        for (int n = 0; n < 4; ++n) {
            const short8 bb = *(const short8*)&Bs[kg * 2048 + (wave * 64 + n * 16 + lrx) * 8];
            acc[0][n] = __builtin_amdgcn_mfma_f32_16x16x32_bf16(a0, bb, acc[0][n], 0, 0, 0);
            acc[1][n] = __builtin_amdgcn_mfma_f32_16x16x32_bf16(a1, bb, acc[1][n], 0, 0, 0);
        }
        __syncthreads();   // reads done before next step's writes (single buffer)
    }

    // epilogue: C/D layout col=lane&15, row=(lane>>4)*4+j  [m89-verified]
#pragma unroll
    for (int m = 0; m < 2; ++m) {
#pragma unroll
        for (int n = 0; n < 4; ++n) {
            const int colg = wave * 64 + n * 16 + lr;
            const float bias = (colg < bsplit) ? biasA[colg] : biasB[colg - bsplit];
#pragma unroll
            for (int j = 0; j < 4; ++j) {
                const int rowg = row0 + m * 16 + kg * 4 + j;
                if (rowg < M) {
                    float o = acc[m][n][j] + bias;
                    if (maskp && maskp[rowg]) o = 0.f;
                    if (obf) ((unsigned short*)Cv)[(size_t)rowg * 256 + colg] = f2bf(o);
                    else     ((float*)Cv)[(size_t)rowg * 256 + colg] = o;
                }
            }
        }
    }
}

// ---------------------------------------------------------------------------
// Box-attention sampling (R21-proven: ~37us). bf16-v + point-split + TLP
// (__launch_bounds__(256,5), unroll 4). Output: split-bf16 [hi|lo].
// ---------------------------------------------------------------------------
#define ROWS 4
#define PP 17

__global__ __launch_bounds__(256, 5) void box_sample(
    const unsigned short* __restrict__ v, // (B*L2, 256) bf16 projected value
    const float* __restrict__ alogp,  // attn logits base (stride 256)
    const float* __restrict__ blgp,   // box logits base (stride 256)
    const float* __restrict__ rwin,
    const float* __restrict__ vratio,
    unsigned short* __restrict__ outs, // (B*L1, 512) split-bf16 out
    int M1, int L1, int L2)
{
    __shared__ int   s_idx[ROWS][NHEAD][PP][4];
    __shared__ float s_w  [ROWS][NHEAD][PP][4];
    __shared__ float s_red[ROWS][NHEAD][4][8];   // point-half reduction (4KB)

    const int row0 = blockIdx.x * ROWS;
    const int tid  = threadIdx.x;

    // ================= phase 1 (first 128 threads) =================
    if (tid < 128) {
        const int l  = tid & 3;
        const int hh = (tid >> 2) & 7;
        const int r  = tid >> 5;
        const int rowq = row0 + r;
        if (rowq < M1) {
            const int b = (rowq >= L1) ? 1 : 0;
            float la[16];
            const float* al = alogp + (size_t)rowq * 256 + hh * 16;
            {
                const float4 q0 = *(const float4*)(al + 0);
                const float4 q1 = *(const float4*)(al + 4);
                const float4 q2 = *(const float4*)(al + 8);
                const float4 q3 = *(const float4*)(al + 12);
                la[0]=q0.x; la[1]=q0.y; la[2]=q0.z; la[3]=q0.w;
                la[4]=q1.x; la[5]=q1.y; la[6]=q1.z; la[7]=q1.w;
                la[8]=q2.x; la[9]=q2.y; la[10]=q2.z; la[11]=q2.w;
                la[12]=q3.x; la[13]=q3.y; la[14]=q3.z; la[15]=q3.w;
            }
            float m = la[0];
#pragma unroll
            for (int i = 1; i < 16; i++) m = fmaxf(m, la[i]);
            float s = 0.f;
#pragma unroll
            for (int i = 0; i < 16; i++) { la[i] = __expf(la[i] - m); s += la[i]; }
            const float inv = 1.f / s;

            const int H  = (l == 0) ? 76 : (l == 1) ? 38 : (l == 2) ? 19 : 10;
            const int W  = H;
            const int s0 = (l == 0) ? 0  : (l == 1) ? 5776 : (l == 2) ? 7220 : 7581;

            const float4 ob = *(const float4*)(blgp + (size_t)rowq * 256 + hh * 16 + l * 4);
            const float4 rw = *(const float4*)(rwin + (size_t)rowq * 4);
            const float vrx = vratio[(b * NLEVEL + l) * 2 + 0];
            const float vry = vratio[(b * NLEVEL + l) * 2 + 1];

            const float cx = rw.x + ob.x * 0.125f * rw.z;
            const float cy = rw.y + ob.y * 0.125f * rw.w;
            const float sw = fmaxf(rw.z + ob.z * 0.125f * rw.z, 0.f);
            const float sh = fmaxf(rw.w + ob.w * 0.125f * rw.w, 0.f);

            const int vbase = (b * L2 + s0) * DMODEL + hh * HDIM;  // ushort units

#pragma unroll
            for (int p = 0; p < 4; ++p) {
                const float kx = (p & 1)  ? 0.25f : -0.25f;
                const float ky = (p >> 1) ? 0.25f : -0.25f;
                const float gx = (cx + kx * sw) * vrx;
                const float gy = (cy + ky * sh) * vry;
                const float x = gx * (float)W - 0.5f;
                const float y = gy * (float)H - 0.5f;
                const float x0f = floorf(x);
                const float y0f = floorf(y);
                const float lx = x - x0f, ly = y - y0f;
                const int x0 = (int)x0f, y0 = (int)y0f;
                const float aw = la[l * 4 + p] * inv;
                const float wb[4] = { (1.f - ly) * (1.f - lx) * aw,
                                      (1.f - ly) * lx * aw,
                                      ly * (1.f - lx) * aw,
                                      ly * lx * aw };
                const int lp = l * 4 + p;
#pragma unroll
                for (int j = 0; j < 4; ++j) {
                    const int yy = y0 + (j >> 1);
                    const int xx = x0 + (j & 1);
                    const bool ok = (yy >= 0) & (yy < H) & (xx >= 0) & (xx < W);
                    const int yc = min(max(yy, 0), H - 1);
                    const int xc = min(max(xx, 0), W - 1);
                    s_idx[r][hh][lp][j] = vbase + (yc * W + xc) * DMODEL;
                    s_w  [r][hh][lp][j] = ok ? wb[j] : 0.f;
                }
            }
        }
    }
    __syncthreads();

    // ================= phase 2: point-split ushort8 gathers =================
    {
        const int oct = tid & 3;            // channel octet 0..3
        const int hh  = (tid >> 2) & 7;     // head
        const int ph  = (tid >> 5) & 1;     // point half
        const int r   = tid >> 6;           // row 0..3
        const int rowq = row0 + r;
        const int c8 = oct << 3;
        float acc[8];
#pragma unroll
        for (int k = 0; k < 8; ++k) acc[k] = 0.f;

        if (rowq < M1) {
            const int p0 = ph << 3;
#pragma unroll 4
            for (int pi = 0; pi < 8; ++pi) {
                const int p = p0 + pi;
                const int4   iv = *(const int4  *)&s_idx[r][hh][p][0];
                const float4 wv = *(const float4*)&s_w  [r][hh][p][0];
                const uint4 g0 = *(const uint4*)(v + iv.x + c8);
                const uint4 g1 = *(const uint4*)(v + iv.y + c8);
                const uint4 g2 = *(const uint4*)(v + iv.z + c8);
                const uint4 g3 = *(const uint4*)(v + iv.w + c8);
                const unsigned int u0[4] = {g0.x, g0.y, g0.z, g0.w};
                const unsigned int u1[4] = {g1.x, g1.y, g1.z, g1.w};
                const unsigned int u2[4] = {g2.x, g2.y, g2.z, g2.w};
                const unsigned int u3[4] = {g3.x, g3.y, g3.z, g3.w};
#pragma unroll
                for (int j = 0; j < 4; ++j) {
                    const float a0 = __uint_as_float(u0[j] << 16);
                    const float b0 = __uint_as_float(u0[j] & 0xffff0000u);
                    const float a1 = __uint_as_float(u1[j] << 16);
                    const float b1 = __uint_as_float(u1[j] & 0xffff0000u);
                    const float a2 = __uint_as_float(u2[j] << 16);
                    const float b2 = __uint_as_float(u2[j] & 0xffff0000u);
                    const float a3 = __uint_as_float(u3[j] << 16);
                    const float b3 = __uint_as_float(u3[j] & 0xffff0000u);
                    acc[j * 2]     += wv.x * a0 + wv.y * a1 + wv.z * a2 + wv.w * a3;
                    acc[j * 2 + 1] += wv.x * b0 + wv.y * b1 + wv.z * b2 + wv.w * b3;
                }
            }
        }

        // reduce the two point-halves via LDS
        if (ph == 1) {
#pragma unroll
            for (int k = 0; k < 8; ++k) s_red[r][hh][oct][k] = acc[k];
        }
        __syncthreads();
        if (ph == 0 && rowq < M1) {
#pragma unroll
            for (int k = 0; k < 8; ++k) acc[k] += s_red[r][hh][oct][k];
            uint4 hi, lo;
            hi.x = pk2(f2bf(acc[0]), f2bf(acc[1]));
            hi.y = pk2(f2bf(acc[2]), f2bf(acc[3]));
            hi.z = pk2(f2bf(acc[4]), f2bf(acc[5]));
            hi.w = pk2(f2bf(acc[6]), f2bf(acc[7]));
            lo.x = pk2(lo1(acc[0]), lo1(acc[1]));
            lo.y = pk2(lo1(acc[2]), lo1(acc[3]));
            lo.z = pk2(lo1(acc[4]), lo1(acc[5]));
            lo.w = pk2(lo1(acc[6]), lo1(acc[7]));
            *(uint4*)(outs + (size_t)rowq * 512 + hh * HDIM + c8)       = hi;
            *(uint4*)(outs + (size_t)rowq * 512 + 256 + hh * HDIM + c8) = lo;
        }
    }
}

// ---------------------------------------------------------------------------
extern "C" void kernel_launch(void* const* d_in, const int* in_sizes, int n_in,
                              void* d_out, int out_size, void* d_ws, size_t ws_size,
                              hipStream_t stream) {
    const float* query   = (const float*)d_in[0];
    const float* value   = (const float*)d_in[1];
    const unsigned char* v_mask = (const unsigned char*)d_in[3];
    const float* v_valid = (const float*)d_in[5];
    const float* ref_win = (const float*)d_in[6];
    const float* vproj_w = (const float*)d_in[7];
    const float* vproj_b = (const float*)d_in[8];
    const float* oproj_w = (const float*)d_in[9];
    const float* oproj_b = (const float*)d_in[10];
    const float* box_w   = (const float*)d_in[11];
    const float* box_b   = (const float*)d_in[12];
    const float* attn_w  = (const float*)d_in[13];
    const float* attn_b  = (const float*)d_in[14];

    const int B  = 2;
    const int M1 = in_sizes[0] / DMODEL;   // B*L1
    const int M2 = in_sizes[1] / DMODEL;   // B*L2
    const int L1 = M1 / B;
    const int L2 = M2 / B;
    const dim3 blk(256);

    // ---- workspace plan: Av | Aq(->OutS) | vprj(bf16) | weights; lgt in d_out
    const size_t szAv = (size_t)M2 * 512 * 2;
    const size_t szAq = (size_t)M1 * 512 * 2;
    char* wsb = (char*)d_ws;
    unsigned short* Av   = (unsigned short*)(wsb);
    unsigned short* Aq   = (unsigned short*)(wsb + szAv);
    unsigned short* OutS = Aq;                       // alias: Aq dead after GEMM
    unsigned short* vprj = (unsigned short*)(wsb + szAv + szAq);   // bf16 M2*256
    unsigned short* Bv   = (unsigned short*)(wsb + szAv + szAq + (size_t)M2 * 256 * 2);
    unsigned short* Bo   = Bv + 256 * 512;
    unsigned short* Blg  = Bo + 256 * 512;
    float*          lgt  = (float*)d_out;            // scratch until final GEMM

    const int mb1 = (M1 + 31) / 32;
    const int mb2 = (M2 + 31) / 32;
    const int nbAct = ((M2 + M1) * 64 + 255) / 256;

    // 1) ALL conversions in one launch (activations + 4 weight matrices)
    convall<<<dim3(nbAct + 192), blk, 0, stream>>>(
        value, query, Av, Aq, M2, M2 + M1, nbAct,
        vproj_w, oproj_w, attn_w, box_w, Bv, Bo, Blg);

    // 2) MERGED: value projection (+mask, bf16 out) AND combined logits (f32)
    gemm_mfma<0><<<dim3(mb2 + mb1), blk, 0, stream>>>(
        Av, Bv, vproj_b, vproj_b, 256, v_mask, (void*)vprj, 1, M2, mb2,
        Aq, Blg, attn_b, box_b, 128, nullptr, (void*)lgt, 0, M1);

    // 3) sampling (bf16 v gathers, point-split, TLP) -> split-bf16
    box_sample<<<dim3((M1 + ROWS - 1) / ROWS), blk, 0, stream>>>(
        vprj, lgt, lgt + 128, ref_win, v_valid, OutS, M1, L1, L2);

    // 4) output projection (reads OutS, overwrites d_out)
    gemm_mfma<1><<<dim3(mb1), blk, 0, stream>>>(
        OutS, Bo, oproj_b, oproj_b, 256, nullptr, d_out, 0, M1, mb1,
        OutS, Bo, oproj_b, oproj_b, 256, nullptr, d_out, 0, M1);
}

// Round 24
// 97.309 us; speedup vs baseline: 1.4545x; 1.0931x over previous
//
#include <hip/hip_runtime.h>
#include <cstdint>
#include <cstddef>

#define NHEAD 8
#define HDIM 32
#define DMODEL 256
#define NLEVEL 4
#define NPOINT 4

using short8 = __attribute__((ext_vector_type(8))) short;
using f32x4  = __attribute__((ext_vector_type(4))) float;

// ---- bf16 helpers (RNE) ----------------------------------------------------
__device__ __forceinline__ unsigned short f2bf(float x) {
    unsigned int b = __float_as_uint(x);
    unsigned int r = b + 0x7FFFu + ((b >> 16) & 1u);
    return (unsigned short)(r >> 16);
}
__device__ __forceinline__ float bf2f(unsigned short u) {
    return __uint_as_float(((unsigned int)u) << 16);
}
__device__ __forceinline__ unsigned short lo1(float v) {
    const unsigned short h = f2bf(v);
    return f2bf(v - bf2f(h));
}
__device__ __forceinline__ unsigned int pk2(unsigned short a, unsigned short b) {
    return (unsigned int)a | ((unsigned int)b << 16);
}

// ---------------------------------------------------------------------------
// convall: ONE launch for all conversions.
//   blocks [0, nbAct): value -> Av, query -> Aq  ([hi|lo] per row)
//   blocks [nbAct, nbAct+192): four weight matrices -> Bv, Bo, Blg
// ---------------------------------------------------------------------------
__global__ __launch_bounds__(256) void convall(
    const float* __restrict__ value, const float* __restrict__ query,
    unsigned short* __restrict__ Av, unsigned short* __restrict__ Aq,
    int M2, int Mtot, int nbAct,
    const float* __restrict__ w0, const float* __restrict__ w1,
    const float* __restrict__ w2, const float* __restrict__ w3,
    unsigned short* __restrict__ b0, unsigned short* __restrict__ b1,
    unsigned short* __restrict__ blg)
{
    if ((int)blockIdx.x < nbAct) {
        const int idx = blockIdx.x * 256 + threadIdx.x;
        if (idx >= Mtot * 64) return;
        const int r = idx >> 6, c = (idx & 63) << 2;
        const float* src;
        unsigned short* dst;
        if (r < M2) { src = value + (size_t)r * 256; dst = Av + (size_t)r * 512; }
        else { src = query + (size_t)(r - M2) * 256; dst = Aq + (size_t)(r - M2) * 512; }
        const float4 v = *(const float4*)(src + c);
        ushort4 hi, lo;
        hi.x = f2bf(v.x); lo.x = lo1(v.x);
        hi.y = f2bf(v.y); lo.y = lo1(v.y);
        hi.z = f2bf(v.z); lo.z = lo1(v.z);
        hi.w = f2bf(v.w); lo.w = lo1(v.w);
        *(ushort4*)(dst + c)       = hi;
        *(ushort4*)(dst + 256 + c) = lo;
    } else {
        const int bx = (int)blockIdx.x - nbAct;           // 0..191
        int y, base;
        if (bx < 64)       { y = 0; base = bx; }
        else if (bx < 128) { y = 1; base = bx - 64; }
        else if (bx < 160) { y = 2; base = bx - 128; }
        else               { y = 3; base = bx - 160; }
        const float* src = (y == 0) ? w0 : (y == 1) ? w1 : (y == 2) ? w2 : w3;
        unsigned short* dst = (y == 0) ? b0 : (y == 1) ? b1 : (y == 2) ? blg : (blg + 128 * 512);
        const int rows = (y < 2) ? 256 : 128;
        const int idx = base * 256 + threadIdx.x;
        if (idx >= rows * 64) return;
        const int r = idx >> 6, c = (idx & 63) << 2;
        const float4 v = *(const float4*)(src + (size_t)r * 256 + c);
        ushort4 hi, lo;
        hi.x = f2bf(v.x); lo.x = lo1(v.x);
        hi.y = f2bf(v.y); lo.y = lo1(v.y);
        hi.z = f2bf(v.z); lo.z = lo1(v.z);
        hi.w = f2bf(v.w); lo.w = lo1(v.w);
        *(ushort4*)(dst + (size_t)r * 512 + c)       = hi;
        *(ushort4*)(dst + (size_t)r * 512 + 256 + c) = lo;
    }
}

// ---------------------------------------------------------------------------
// Split-bf16 MFMA GEMM, BM=32 x BN=256, BK=64, 12 K-steps, single-buffered,
// register prefetch (R22 proved gload_lds serializes; R21 structure kept).
// R23 showed the GEMM is GRID-limited (2.8 blocks/CU, occ 32%): halving the
// barrier count (24->12 steps) doubles per-step work (16 MFMA + 12 ds_read
// between barriers) and doubles the prefetch latency-hiding window.
// LDS 36KB: [slot 0..7][rows][8] per operand; swizzle phys_row = row^(slot<<1)
// (bank-group audit: writes & reads both 2-way = free). K'=768 = 12x64:
// A segs [hi,hi,lo] x B segs [hi,lo,hi] (C = AhBh+AhBl+AlBh).
// Two sub-GEMMs merged per launch. obf: bf16 C-write for vprj.
// ---------------------------------------------------------------------------
template<int ID>
__global__ __launch_bounds__(256, 4) void gemm_mfma(
    const unsigned short* __restrict__ A0, const unsigned short* __restrict__ B0,
    const float* __restrict__ bsA0, const float* __restrict__ bsB0, int bsplit0,
    const unsigned char* __restrict__ mask0, void* __restrict__ C0, int obf0, int M0, int nb0,
    const unsigned short* __restrict__ A1, const unsigned short* __restrict__ B1,
    const float* __restrict__ bsA1, const float* __restrict__ bsB1, int bsplit1,
    const unsigned char* __restrict__ mask1, void* __restrict__ C1, int obf1, int M1)
{
    __shared__ __align__(16) unsigned short As[8 * 32 * 8];    // 4KB  [slot][32][8]
    __shared__ __align__(16) unsigned short Bs[8 * 256 * 8];   // 32KB [slot][256][8]

    const bool second = ((int)blockIdx.x >= nb0);
    const unsigned short* Abf = second ? A1 : A0;
    const unsigned short* Bbf = second ? B1 : B0;
    const float* biasA = second ? bsA1 : bsA0;
    const float* biasB = second ? bsB1 : bsB0;
    const int bsplit   = second ? bsplit1 : bsplit0;
    const unsigned char* maskp = second ? mask1 : mask0;
    void* Cv    = second ? C1 : C0;
    const int obf = second ? obf1 : obf0;
    const int M = second ? M1 : M0;
    const int row0 = (second ? ((int)blockIdx.x - nb0) : (int)blockIdx.x) * 32;

    const int tid  = threadIdx.x;
    const int lane = tid & 63;
    const int wave = tid >> 6;          // 0..3 -> cols wave*64..+64
    const int lr = lane & 15;
    const int kg = lane >> 4;           // 0..3 k-octet group within K=32

    // staging maps (1 A + 8 B loads per thread)
    const int as = tid & 7;             // A slot 0..7
    const int ar = tid >> 3;            // A row 0..31
    const int arx = ar ^ (as << 1);
    const int bs = tid & 7;             // B slot 0..7
    const int br = tid >> 3;            // B row base 0..31 (8 rows stride 32)

    const unsigned short* pA = Abf + (size_t)min(row0 + ar, M - 1) * 512 + as * 8;
    const unsigned short* pB = Bbf + (size_t)br * 512 + bs * 8;

    f32x4 acc[2][4];
#pragma unroll
    for (int m = 0; m < 2; ++m)
#pragma unroll
        for (int n = 0; n < 4; ++n) acc[m][n] = {0.f, 0.f, 0.f, 0.f};

    // prefetch step 0 (seg0: aoff=boff=0)
    uint4 va, vb0, vb1, vb2, vb3, vb4, vb5, vb6, vb7;
    va  = *(const uint4*)pA;
    vb0 = *(const uint4*)(pB                   );
    vb1 = *(const uint4*)(pB + (size_t) 32*512);
    vb2 = *(const uint4*)(pB + (size_t) 64*512);
    vb3 = *(const uint4*)(pB + (size_t) 96*512);
    vb4 = *(const uint4*)(pB + (size_t)128*512);
    vb5 = *(const uint4*)(pB + (size_t)160*512);
    vb6 = *(const uint4*)(pB + (size_t)192*512);
    vb7 = *(const uint4*)(pB + (size_t)224*512);

    for (int st = 0; st < 12; ++st) {
        *(uint4*)&As[as * 256 + arx * 8] = va;
        *(uint4*)&Bs[bs * 2048 + (((br      ) ^ (bs << 1))      ) * 8] = vb0;
        *(uint4*)&Bs[bs * 2048 + (((br      ) ^ (bs << 1)) +  32) * 8] = vb1;
        *(uint4*)&Bs[bs * 2048 + (((br      ) ^ (bs << 1)) +  64) * 8] = vb2;
        *(uint4*)&Bs[bs * 2048 + (((br      ) ^ (bs << 1)) +  96) * 8] = vb3;
        *(uint4*)&Bs[bs * 2048 + (((br      ) ^ (bs << 1)) + 128) * 8] = vb4;
        *(uint4*)&Bs[bs * 2048 + (((br      ) ^ (bs << 1)) + 160) * 8] = vb5;
        *(uint4*)&Bs[bs * 2048 + (((br      ) ^ (bs << 1)) + 192) * 8] = vb6;
        *(uint4*)&Bs[bs * 2048 + (((br      ) ^ (bs << 1)) + 224) * 8] = vb7;
        __syncthreads();   // writes visible before reads

        if (st < 11) {     // issue next step's loads; hide under 16 MFMAs
            const int sn   = st + 1;
            const int seg  = sn >> 2;                 // 0..2
            const int kl   = (sn & 3) << 6;           // 0,64,128,192 (ushort)
            const int aoff = (seg < 2)  ? kl : 256 + kl;   // A: [hi,hi,lo]
            const int boff = (seg == 1) ? 256 + kl : kl;   // B: [hi,lo,hi]
            va  = *(const uint4*)(pA + aoff);
            vb0 = *(const uint4*)(pB + boff                   );
            vb1 = *(const uint4*)(pB + boff + (size_t) 32*512);
            vb2 = *(const uint4*)(pB + boff + (size_t) 64*512);
            vb3 = *(const uint4*)(pB + boff + (size_t) 96*512);
            vb4 = *(const uint4*)(pB + boff + (size_t)128*512);
            vb5 = *(const uint4*)(pB + boff + (size_t)160*512);
            vb6 = *(const uint4*)(pB + boff + (size_t)192*512);
            vb7 = *(const uint4*)(pB + boff + (size_t)224*512);
        }

#pragma unroll
        for (int ks = 0; ks < 2; ++ks) {
            const int sA = ks * 4 + kg;               // octet slot 0..7
            const int rx = lr ^ (sA << 1);
            const short8 a0 = *(const short8*)&As[sA * 256 + (rx     ) * 8];
            const short8 a1 = *(const short8*)&As[sA * 256 + (rx + 16) * 8];
#pragma unroll
            for (int n = 0; n < 4; ++n) {
                const short8 bb = *(const short8*)&Bs[sA * 2048 + (wave * 64 + n * 16 + rx) * 8];
                acc[0][n] = __builtin_amdgcn_mfma_f32_16x16x32_bf16(a0, bb, acc[0][n], 0, 0, 0);
                acc[1][n] = __builtin_amdgcn_mfma_f32_16x16x32_bf16(a1, bb, acc[1][n], 0, 0, 0);
            }
        }
        __syncthreads();   // reads done before next step's writes
    }

    // epilogue: C/D layout col=lane&15, row=(lane>>4)*4+j  [m89-verified]
#pragma unroll
    for (int m = 0; m < 2; ++m) {
#pragma unroll
        for (int n = 0; n < 4; ++n) {
            const int colg = wave * 64 + n * 16 + lr;
            const float bias = (colg < bsplit) ? biasA[colg] : biasB[colg - bsplit];
#pragma unroll
            for (int j = 0; j < 4; ++j) {
                const int rowg = row0 + m * 16 + kg * 4 + j;
                if (rowg < M) {
                    float o = acc[m][n][j] + bias;
                    if (maskp && maskp[rowg]) o = 0.f;
                    if (obf) ((unsigned short*)Cv)[(size_t)rowg * 256 + colg] = f2bf(o);
                    else     ((float*)Cv)[(size_t)rowg * 256 + colg] = o;
                }
            }
        }
    }
}

// ---------------------------------------------------------------------------
// Box-attention sampling (R21-proven: ~37us). bf16-v + point-split + TLP
// (__launch_bounds__(256,5), unroll 4). Output: split-bf16 [hi|lo].
// ---------------------------------------------------------------------------
#define ROWS 4
#define PP 17

__global__ __launch_bounds__(256, 5) void box_sample(
    const unsigned short* __restrict__ v, // (B*L2, 256) bf16 projected value
    const float* __restrict__ alogp,  // attn logits base (stride 256)
    const float* __restrict__ blgp,   // box logits base (stride 256)
    const float* __restrict__ rwin,
    const float* __restrict__ vratio,
    unsigned short* __restrict__ outs, // (B*L1, 512) split-bf16 out
    int M1, int L1, int L2)
{
    __shared__ int   s_idx[ROWS][NHEAD][PP][4];
    __shared__ float s_w  [ROWS][NHEAD][PP][4];
    __shared__ float s_red[ROWS][NHEAD][4][8];   // point-half reduction (4KB)

    const int row0 = blockIdx.x * ROWS;
    const int tid  = threadIdx.x;

    // ================= phase 1 (first 128 threads) =================
    if (tid < 128) {
        const int l  = tid & 3;
        const int hh = (tid >> 2) & 7;
        const int r  = tid >> 5;
        const int rowq = row0 + r;
        if (rowq < M1) {
            const int b = (rowq >= L1) ? 1 : 0;
            float la[16];
            const float* al = alogp + (size_t)rowq * 256 + hh * 16;
            {
                const float4 q0 = *(const float4*)(al + 0);
                const float4 q1 = *(const float4*)(al + 4);
                const float4 q2 = *(const float4*)(al + 8);
                const float4 q3 = *(const float4*)(al + 12);
                la[0]=q0.x; la[1]=q0.y; la[2]=q0.z; la[3]=q0.w;
                la[4]=q1.x; la[5]=q1.y; la[6]=q1.z; la[7]=q1.w;
                la[8]=q2.x; la[9]=q2.y; la[10]=q2.z; la[11]=q2.w;
                la[12]=q3.x; la[13]=q3.y; la[14]=q3.z; la[15]=q3.w;
            }
            float m = la[0];
#pragma unroll
            for (int i = 1; i < 16; i++) m = fmaxf(m, la[i]);
            float s = 0.f;
#pragma unroll
            for (int i = 0; i < 16; i++) { la[i] = __expf(la[i] - m); s += la[i]; }
            const float inv = 1.f / s;

            const int H  = (l == 0) ? 76 : (l == 1) ? 38 : (l == 2) ? 19 : 10;
            const int W  = H;
            const int s0 = (l == 0) ? 0  : (l == 1) ? 5776 : (l == 2) ? 7220 : 7581;

            const float4 ob = *(const float4*)(blgp + (size_t)rowq * 256 + hh * 16 + l * 4);
            const float4 rw = *(const float4*)(rwin + (size_t)rowq * 4);
            const float vrx = vratio[(b * NLEVEL + l) * 2 + 0];
            const float vry = vratio[(b * NLEVEL + l) * 2 + 1];

            const float cx = rw.x + ob.x * 0.125f * rw.z;
            const float cy = rw.y + ob.y * 0.125f * rw.w;
            const float sw = fmaxf(rw.z + ob.z * 0.125f * rw.z, 0.f);
            const float sh = fmaxf(rw.w + ob.w * 0.125f * rw.w, 0.f);

            const int vbase = (b * L2 + s0) * DMODEL + hh * HDIM;  // ushort units

#pragma unroll
            for (int p = 0; p < 4; ++p) {
                const float kx = (p & 1)  ? 0.25f : -0.25f;
                const float ky = (p >> 1) ? 0.25f : -0.25f;
                const float gx = (cx + kx * sw) * vrx;
                const float gy = (cy + ky * sh) * vry;
                const float x = gx * (float)W - 0.5f;
                const float y = gy * (float)H - 0.5f;
                const float x0f = floorf(x);
                const float y0f = floorf(y);
                const float lx = x - x0f, ly = y - y0f;
                const int x0 = (int)x0f, y0 = (int)y0f;
                const float aw = la[l * 4 + p] * inv;
                const float wb[4] = { (1.f - ly) * (1.f - lx) * aw,
                                      (1.f - ly) * lx * aw,
                                      ly * (1.f - lx) * aw,
                                      ly * lx * aw };
                const int lp = l * 4 + p;
#pragma unroll
                for (int j = 0; j < 4; ++j) {
                    const int yy = y0 + (j >> 1);
                    const int xx = x0 + (j & 1);
                    const bool ok = (yy >= 0) & (yy < H) & (xx >= 0) & (xx < W);
                    const int yc = min(max(yy, 0), H - 1);
                    const int xc = min(max(xx, 0), W - 1);
                    s_idx[r][hh][lp][j] = vbase + (yc * W + xc) * DMODEL;
                    s_w  [r][hh][lp][j] = ok ? wb[j] : 0.f;
                }
            }
        }
    }
    __syncthreads();

    // ================= phase 2: point-split ushort8 gathers =================
    {
        const int oct = tid & 3;            // channel octet 0..3
        const int hh  = (tid >> 2) & 7;     // head
        const int ph  = (tid >> 5) & 1;     // point half
        const int r   = tid >> 6;           // row 0..3
        const int rowq = row0 + r;
        const int c8 = oct << 3;
        float acc[8];
#pragma unroll
        for (int k = 0; k < 8; ++k) acc[k] = 0.f;

        if (rowq < M1) {
            const int p0 = ph << 3;
#pragma unroll 4
            for (int pi = 0; pi < 8; ++pi) {
                const int p = p0 + pi;
                const int4   iv = *(const int4  *)&s_idx[r][hh][p][0];
                const float4 wv = *(const float4*)&s_w  [r][hh][p][0];
                const uint4 g0 = *(const uint4*)(v + iv.x + c8);
                const uint4 g1 = *(const uint4*)(v + iv.y + c8);
                const uint4 g2 = *(const uint4*)(v + iv.z + c8);
                const uint4 g3 = *(const uint4*)(v + iv.w + c8);
                const unsigned int u0[4] = {g0.x, g0.y, g0.z, g0.w};
                const unsigned int u1[4] = {g1.x, g1.y, g1.z, g1.w};
                const unsigned int u2[4] = {g2.x, g2.y, g2.z, g2.w};
                const unsigned int u3[4] = {g3.x, g3.y, g3.z, g3.w};
#pragma unroll
                for (int j = 0; j < 4; ++j) {
                    const float a0 = __uint_as_float(u0[j] << 16);
                    const float b0 = __uint_as_float(u0[j] & 0xffff0000u);
                    const float a1 = __uint_as_float(u1[j] << 16);
                    const float b1 = __uint_as_float(u1[j] & 0xffff0000u);
                    const float a2 = __uint_as_float(u2[j] << 16);
                    const float b2 = __uint_as_float(u2[j] & 0xffff0000u);
                    const float a3 = __uint_as_float(u3[j] << 16);
                    const float b3 = __uint_as_float(u3[j] & 0xffff0000u);
                    acc[j * 2]     += wv.x * a0 + wv.y * a1 + wv.z * a2 + wv.w * a3;
                    acc[j * 2 + 1] += wv.x * b0 + wv.y * b1 + wv.z * b2 + wv.w * b3;
                }
            }
        }

        // reduce the two point-halves via LDS
        if (ph == 1) {
#pragma unroll
            for (int k = 0; k < 8; ++k) s_red[r][hh][oct][k] = acc[k];
        }
        __syncthreads();
        if (ph == 0 && rowq < M1) {
#pragma unroll
            for (int k = 0; k < 8; ++k) acc[k] += s_red[r][hh][oct][k];
            uint4 hi, lo;
            hi.x = pk2(f2bf(acc[0]), f2bf(acc[1]));
            hi.y = pk2(f2bf(acc[2]), f2bf(acc[3]));
            hi.z = pk2(f2bf(acc[4]), f2bf(acc[5]));
            hi.w = pk2(f2bf(acc[6]), f2bf(acc[7]));
            lo.x = pk2(lo1(acc[0]), lo1(acc[1]));
            lo.y = pk2(lo1(acc[2]), lo1(acc[3]));
            lo.z = pk2(lo1(acc[4]), lo1(acc[5]));
            lo.w = pk2(lo1(acc[6]), lo1(acc[7]));
            *(uint4*)(outs + (size_t)rowq * 512 + hh * HDIM + c8)       = hi;
            *(uint4*)(outs + (size_t)rowq * 512 + 256 + hh * HDIM + c8) = lo;
        }
    }
}

// ---------------------------------------------------------------------------
extern "C" void kernel_launch(void* const* d_in, const int* in_sizes, int n_in,
                              void* d_out, int out_size, void* d_ws, size_t ws_size,
                              hipStream_t stream) {
    const float* query   = (const float*)d_in[0];
    const float* value   = (const float*)d_in[1];
    const unsigned char* v_mask = (const unsigned char*)d_in[3];
    const float* v_valid = (const float*)d_in[5];
    const float* ref_win = (const float*)d_in[6];
    const float* vproj_w = (const float*)d_in[7];
    const float* vproj_b = (const float*)d_in[8];
    const float* oproj_w = (const float*)d_in[9];
    const float* oproj_b = (const float*)d_in[10];
    const float* box_w   = (const float*)d_in[11];
    const float* box_b   = (const float*)d_in[12];
    const float* attn_w  = (const float*)d_in[13];
    const float* attn_b  = (const float*)d_in[14];

    const int B  = 2;
    const int M1 = in_sizes[0] / DMODEL;   // B*L1
    const int M2 = in_sizes[1] / DMODEL;   // B*L2
    const int L1 = M1 / B;
    const int L2 = M2 / B;
    const dim3 blk(256);

    // ---- workspace plan: Av | Aq(->OutS) | vprj(bf16) | weights; lgt in d_out
    const size_t szAv = (size_t)M2 * 512 * 2;
    const size_t szAq = (size_t)M1 * 512 * 2;
    char* wsb = (char*)d_ws;
    unsigned short* Av   = (unsigned short*)(wsb);
    unsigned short* Aq   = (unsigned short*)(wsb + szAv);
    unsigned short* OutS = Aq;                       // alias: Aq dead after GEMM
    unsigned short* vprj = (unsigned short*)(wsb + szAv + szAq);   // bf16 M2*256
    unsigned short* Bv   = (unsigned short*)(wsb + szAv + szAq + (size_t)M2 * 256 * 2);
    unsigned short* Bo   = Bv + 256 * 512;
    unsigned short* Blg  = Bo + 256 * 512;
    float*          lgt  = (float*)d_out;            // scratch until final GEMM

    const int mb1 = (M1 + 31) / 32;
    const int mb2 = (M2 + 31) / 32;
    const int nbAct = ((M2 + M1) * 64 + 255) / 256;

    // 1) ALL conversions in one launch (activations + 4 weight matrices)
    convall<<<dim3(nbAct + 192), blk, 0, stream>>>(
        value, query, Av, Aq, M2, M2 + M1, nbAct,
        vproj_w, oproj_w, attn_w, box_w, Bv, Bo, Blg);

    // 2) MERGED: value projection (+mask, bf16 out) AND combined logits (f32)
    gemm_mfma<0><<<dim3(mb2 + mb1), blk, 0, stream>>>(
        Av, Bv, vproj_b, vproj_b, 256, v_mask, (void*)vprj, 1, M2, mb2,
        Aq, Blg, attn_b, box_b, 128, nullptr, (void*)lgt, 0, M1);

    // 3) sampling (bf16 v gathers, point-split, TLP) -> split-bf16
    box_sample<<<dim3((M1 + ROWS - 1) / ROWS), blk, 0, stream>>>(
        vprj, lgt, lgt + 128, ref_win, v_valid, OutS, M1, L1, L2);

    // 4) output projection (reads OutS, overwrites d_out)
    gemm_mfma<1><<<dim3(mb1), blk, 0, stream>>>(
        OutS, Bo, oproj_b, oproj_b, 256, nullptr, d_out, 0, M1, mb1,
        OutS, Bo, oproj_b, oproj_b, 256, nullptr, d_out, 0, M1);
}